// Round 1
// baseline (21691.515 us; speedup 1.0000x reference)
//
#include <hip/hip_runtime.h>
#include <cstddef>

#define D 1024
#define H 16
#define KS 64
#define S 2048
#define B 2
#define M_ROWS (B * S)   // 4096

// ---------------------------------------------------------------------------
// Tiled fp32 GEMM: C[M_ROWS, D] = A[M_ROWS, D] @ W[D, D] + bias
// permute==1: write C[(b*H+h)*S*64 + s*64 + d] (i.e. [B,H,S,64] layout),
//             where row = b*S+s, col = h*64+d.
// permute==0: write C[row*D + col] (standard row-major).
// BM=BN=64, BK=16, 256 threads, 4x4 micro-tile per thread.
// ---------------------------------------------------------------------------
__global__ __launch_bounds__(256) void gemm_proj(
    const float* __restrict__ A, const float* __restrict__ W,
    const float* __restrict__ bias, float* __restrict__ C, int permute)
{
    __shared__ float As[64][16];
    __shared__ float Bs[16][64];

    const int tile_m = blockIdx.y * 64;
    const int tile_n = blockIdx.x * 64;
    const int tid = threadIdx.x;
    const int tx = tid & 15;        // 0..15 -> N
    const int ty = tid >> 4;        // 0..15 -> M

    float acc[4][4];
#pragma unroll
    for (int i = 0; i < 4; i++)
#pragma unroll
        for (int j = 0; j < 4; j++) acc[i][j] = 0.0f;

    for (int k0 = 0; k0 < D; k0 += 16) {
        // stage A tile: 64x16 = 1024 floats, 4 per thread
#pragma unroll
        for (int i = 0; i < 4; i++) {
            int idx = tid + i * 256;
            int r = idx >> 4, c = idx & 15;
            As[r][c] = A[(size_t)(tile_m + r) * D + k0 + c];
        }
        // stage W tile: 16x64
#pragma unroll
        for (int i = 0; i < 4; i++) {
            int idx = tid + i * 256;
            int r = idx >> 6, c = idx & 63;
            Bs[r][c] = W[(size_t)(k0 + r) * D + tile_n + c];
        }
        __syncthreads();
#pragma unroll
        for (int kk = 0; kk < 16; kk++) {
            float a[4], b[4];
#pragma unroll
            for (int i = 0; i < 4; i++) a[i] = As[ty * 4 + i][kk];
#pragma unroll
            for (int j = 0; j < 4; j++) b[j] = Bs[kk][tx * 4 + j];
#pragma unroll
            for (int i = 0; i < 4; i++)
#pragma unroll
                for (int j = 0; j < 4; j++) acc[i][j] += a[i] * b[j];
        }
        __syncthreads();
    }

#pragma unroll
    for (int i = 0; i < 4; i++) {
        int row = tile_m + ty * 4 + i;       // b*S + s
#pragma unroll
        for (int j = 0; j < 4; j++) {
            int col = tile_n + tx * 4 + j;   // h*64 + d
            float val = acc[i][j] + bias[col];
            if (permute) {
                int bb = row >> 11, ss = row & (S - 1);
                int hh = col >> 6, dd = col & 63;
                C[(((size_t)(bb * H + hh) * S + ss) << 6) + dd] = val;
            } else {
                C[(size_t)row * D + col] = val;
            }
        }
    }
}

// ---------------------------------------------------------------------------
// Attention: one block per (qi, h, b). 256 threads.
// Q,K,V in [B,H,S,64] layout. Writes alignment row to align_out,
// context to ctx_out in [B*S, D] layout (col = h*64+d) for the final GEMM.
// ---------------------------------------------------------------------------
__global__ __launch_bounds__(256) void attn(
    const float* __restrict__ Q, const float* __restrict__ K,
    const float* __restrict__ V, const float* __restrict__ mask,
    float* __restrict__ align_out, float* __restrict__ ctx_out)
{
    const int qi = blockIdx.x;
    const int h  = blockIdx.y;
    const int b  = blockIdx.z;
    const int tid = threadIdx.x;

    __shared__ float sQ[64];
    __shared__ float sP[S];
    __shared__ float red[256];

    const size_t head_base = ((size_t)(b * H + h) * S) << 6;  // *64
    const float* qrow = Q + head_base + ((size_t)qi << 6);
    if (tid < 64) sQ[tid] = qrow[tid];
    __syncthreads();

    const float* Kh = K + head_base;
    const float* mrow = mask + ((size_t)b * S + qi) * S;

    // ---- scores + mask semantics ----
    float lmax = -1e30f;
#pragma unroll
    for (int i = 0; i < 8; i++) {
        int k = tid + i * 256;
        const float* krow = Kh + ((size_t)k << 6);
        float dot = 0.0f;
#pragma unroll
        for (int d = 0; d < 64; d++) dot += sQ[d] * krow[d];
        float sc = dot * 0.125f;          // 1/sqrt(64)
        sc = sc * mrow[k];                 // multiply by mask
        if (sc == 0.0f) sc = -1.0e9f;      // exact-zero -> NEG_BIG
        sP[k] = sc;
        lmax = fmaxf(lmax, sc);
    }

    // ---- block max ----
    red[tid] = lmax;
    __syncthreads();
    for (int s = 128; s > 0; s >>= 1) {
        if (tid < s) red[tid] = fmaxf(red[tid], red[tid + s]);
        __syncthreads();
    }
    const float m = red[0];
    __syncthreads();

    // ---- exp + sum ----
    float lsum = 0.0f;
#pragma unroll
    for (int i = 0; i < 8; i++) {
        int k = tid + i * 256;
        float e = __expf(sP[k] - m);
        sP[k] = e;
        lsum += e;
    }
    red[tid] = lsum;
    __syncthreads();
    for (int s = 128; s > 0; s >>= 1) {
        if (tid < s) red[tid] += red[tid + s];
        __syncthreads();
    }
    const float inv = 1.0f / red[0];
    __syncthreads();

    // ---- normalize + write alignment ----
    float* arow = align_out + (((size_t)(b * H + h) * S + qi) * S);
#pragma unroll
    for (int i = 0; i < 8; i++) {
        int k = tid + i * 256;
        float p = sP[k] * inv;
        sP[k] = p;
        arow[k] = p;
    }
    __syncthreads();

    // ---- context = P @ V ----
    const float* Vh = V + head_base;
    const int d = tid & 63;
    const int chunk = tid >> 6;            // 0..3, each 512 k's
    float c = 0.0f;
    const int k_beg = chunk * 512;
    for (int k = k_beg; k < k_beg + 512; k++) {
        c += sP[k] * Vh[((size_t)k << 6) + d];
    }
    red[tid] = c;
    __syncthreads();
    if (tid < 64) {
        float sum = red[tid] + red[tid + 64] + red[tid + 128] + red[tid + 192];
        ctx_out[((size_t)(b * S + qi)) * D + h * 64 + d] = sum;
    }
}

// ---------------------------------------------------------------------------
extern "C" void kernel_launch(void* const* d_in, const int* in_sizes, int n_in,
                              void* d_out, int out_size, void* d_ws, size_t ws_size,
                              hipStream_t stream)
{
    const float* q     = (const float*)d_in[0];
    const float* v     = (const float*)d_in[1];
    const float* mask  = (const float*)d_in[2];
    const float* wq_w  = (const float*)d_in[3];
    const float* wq_b  = (const float*)d_in[4];
    const float* wk_w  = (const float*)d_in[5];
    const float* wk_b  = (const float*)d_in[6];
    const float* wv_w  = (const float*)d_in[7];
    const float* wv_b  = (const float*)d_in[8];
    const float* wo_w  = (const float*)d_in[9];
    const float* wo_b  = (const float*)d_in[10];

    float* out_heads = (float*)d_out;                       // [B,S,D]
    float* out_align = (float*)d_out + (size_t)B * S * D;   // [B,H,S,S]

    const size_t qkv_elems = (size_t)B * H * S * KS;        // 4,194,304
    float* Qw  = (float*)d_ws;
    float* Kw  = Qw + qkv_elems;
    float* Vw  = Kw + qkv_elems;
    float* Ctx = Vw + qkv_elems;                            // [B*S, D]

    dim3 gemm_grid(D / 64, M_ROWS / 64);   // (16, 64)
    gemm_proj<<<gemm_grid, 256, 0, stream>>>(q, wq_w, wq_b, Qw, 1);
    gemm_proj<<<gemm_grid, 256, 0, stream>>>(v, wk_w, wk_b, Kw, 1);
    gemm_proj<<<gemm_grid, 256, 0, stream>>>(v, wv_w, wv_b, Vw, 1);

    dim3 attn_grid(S, H, B);               // (2048, 16, 2)
    attn<<<attn_grid, 256, 0, stream>>>(Qw, Kw, Vw, mask, out_align, Ctx);

    gemm_proj<<<gemm_grid, 256, 0, stream>>>(Ctx, wo_w, wo_b, out_heads, 0);
}

// Round 2
// 1825.283 us; speedup vs baseline: 11.8839x; 11.8839x over previous
//
#include <hip/hip_runtime.h>
#include <cstddef>

#define D 1024
#define H 16
#define KS 64
#define S 2048
#define B 2
#define M_ROWS (B * S)   // 4096

// ---------------------------------------------------------------------------
// Tiled fp32 GEMM: C[M_ROWS, D] = A[M_ROWS, D] @ W[D, D] + bias
// permute==1: write C in [B,H,S,64] layout (row=b*S+s, col=h*64+d).
// permute==0: standard row-major.
// ---------------------------------------------------------------------------
__global__ __launch_bounds__(256) void gemm_proj(
    const float* __restrict__ A, const float* __restrict__ W,
    const float* __restrict__ bias, float* __restrict__ C, int permute)
{
    __shared__ float As[64][16];
    __shared__ float Bs[16][64];

    const int tile_m = blockIdx.y * 64;
    const int tile_n = blockIdx.x * 64;
    const int tid = threadIdx.x;
    const int tx = tid & 15;
    const int ty = tid >> 4;

    float acc[4][4];
#pragma unroll
    for (int i = 0; i < 4; i++)
#pragma unroll
        for (int j = 0; j < 4; j++) acc[i][j] = 0.0f;

    for (int k0 = 0; k0 < D; k0 += 16) {
#pragma unroll
        for (int i = 0; i < 4; i++) {
            int idx = tid + i * 256;
            int r = idx >> 4, c = idx & 15;
            As[r][c] = A[(size_t)(tile_m + r) * D + k0 + c];
        }
#pragma unroll
        for (int i = 0; i < 4; i++) {
            int idx = tid + i * 256;
            int r = idx >> 6, c = idx & 63;
            Bs[r][c] = W[(size_t)(k0 + r) * D + tile_n + c];
        }
        __syncthreads();
#pragma unroll
        for (int kk = 0; kk < 16; kk++) {
            float a[4], b[4];
#pragma unroll
            for (int i = 0; i < 4; i++) a[i] = As[ty * 4 + i][kk];
#pragma unroll
            for (int j = 0; j < 4; j++) b[j] = Bs[kk][tx * 4 + j];
#pragma unroll
            for (int i = 0; i < 4; i++)
#pragma unroll
                for (int j = 0; j < 4; j++) acc[i][j] += a[i] * b[j];
        }
        __syncthreads();
    }

#pragma unroll
    for (int i = 0; i < 4; i++) {
        int row = tile_m + ty * 4 + i;
#pragma unroll
        for (int j = 0; j < 4; j++) {
            int col = tile_n + tx * 4 + j;
            float val = acc[i][j] + bias[col];
            if (permute) {
                int bb = row >> 11, ss = row & (S - 1);
                int hh = col >> 6, dd = col & 63;
                C[(((size_t)(bb * H + hh) * S + ss) << 6) + dd] = val;
            } else {
                C[(size_t)row * D + col] = val;
            }
        }
    }
}

// ---------------------------------------------------------------------------
// scores: per (b,h) GEMM  Sc[m][n] = scale * Q[m]·K[n], then mask semantics.
// Q,K in [B,H,S,64]. Sc row-major [B,H,S,S] (written raw/masked; softmax
// kernel normalizes in place).
// grid (S/64 key-tiles, S/64 query-tiles, B*H), 256 threads, 4x4 micro-tile.
// ---------------------------------------------------------------------------
__global__ __launch_bounds__(256) void scores_kernel(
    const float* __restrict__ Q, const float* __restrict__ K,
    const float* __restrict__ mask, float* __restrict__ Sc)
{
    const int bh     = blockIdx.z;          // b*H + h
    const int tile_m = blockIdx.y * 64;     // query tile
    const int tile_n = blockIdx.x * 64;     // key tile
    const int b      = bh >> 4;
    const int tid = threadIdx.x;
    const int tx = tid & 15;
    const int ty = tid >> 4;

    __shared__ float As[64][16];   // Q tile [m][k]
    __shared__ float Bs[16][65];   // K tile transposed [k][n], pad 65

    const float* Qh = Q + (((size_t)bh * S) << 6);
    const float* Kh = K + (((size_t)bh * S) << 6);

    float acc[4][4];
#pragma unroll
    for (int i = 0; i < 4; i++)
#pragma unroll
        for (int j = 0; j < 4; j++) acc[i][j] = 0.0f;

    for (int k0 = 0; k0 < KS; k0 += 16) {
#pragma unroll
        for (int i = 0; i < 4; i++) {
            int idx = tid + i * 256;
            int r = idx >> 4, c = idx & 15;
            As[r][c] = Qh[((size_t)(tile_m + r) << 6) + k0 + c];
        }
#pragma unroll
        for (int i = 0; i < 4; i++) {
            int idx = tid + i * 256;
            int rK = idx >> 4, cK = idx & 15;   // coalesced read of K row segment
            Bs[cK][rK] = Kh[((size_t)(tile_n + rK) << 6) + k0 + cK];
        }
        __syncthreads();
#pragma unroll
        for (int kk = 0; kk < 16; kk++) {
            float a[4], bb[4];
#pragma unroll
            for (int i = 0; i < 4; i++) a[i] = As[ty * 4 + i][kk];
#pragma unroll
            for (int j = 0; j < 4; j++) bb[j] = Bs[kk][tx * 4 + j];
#pragma unroll
            for (int i = 0; i < 4; i++)
#pragma unroll
                for (int j = 0; j < 4; j++) acc[i][j] += a[i] * bb[j];
        }
        __syncthreads();
    }

    const float* mb = mask + (size_t)b * S * S;   // mask[b,1,S,S]
    float* Sh = Sc + (size_t)bh * S * S;
#pragma unroll
    for (int i = 0; i < 4; i++) {
        int m = tile_m + ty * 4 + i;
#pragma unroll
        for (int j = 0; j < 4; j++) {
            int n = tile_n + tx * 4 + j;
            float sc = acc[i][j] * 0.125f;            // 1/sqrt(64)
            sc *= mb[(size_t)m * S + n];
            if (sc == 0.0f) sc = -1.0e9f;
            Sh[(size_t)m * S + n] = sc;
        }
    }
}

// ---------------------------------------------------------------------------
// softmax in place over rows of length S. One block per row, 256 threads.
// ---------------------------------------------------------------------------
__global__ __launch_bounds__(256) void softmax_kernel(float* __restrict__ P)
{
    const size_t row = blockIdx.x;
    float* p = P + row * S;
    const int tid = threadIdx.x;

    float4 x0 = ((float4*)p)[tid];
    float4 x1 = ((float4*)p)[tid + 256];

    float lmax = fmaxf(fmaxf(fmaxf(x0.x, x0.y), fmaxf(x0.z, x0.w)),
                       fmaxf(fmaxf(x1.x, x1.y), fmaxf(x1.z, x1.w)));

    __shared__ float red[256];
    red[tid] = lmax;
    __syncthreads();
    for (int s = 128; s > 0; s >>= 1) {
        if (tid < s) red[tid] = fmaxf(red[tid], red[tid + s]);
        __syncthreads();
    }
    const float m = red[0];
    __syncthreads();

    x0.x = __expf(x0.x - m); x0.y = __expf(x0.y - m);
    x0.z = __expf(x0.z - m); x0.w = __expf(x0.w - m);
    x1.x = __expf(x1.x - m); x1.y = __expf(x1.y - m);
    x1.z = __expf(x1.z - m); x1.w = __expf(x1.w - m);

    float lsum = (x0.x + x0.y + x0.z + x0.w) + (x1.x + x1.y + x1.z + x1.w);
    red[tid] = lsum;
    __syncthreads();
    for (int s = 128; s > 0; s >>= 1) {
        if (tid < s) red[tid] += red[tid + s];
        __syncthreads();
    }
    const float inv = 1.0f / red[0];

    x0.x *= inv; x0.y *= inv; x0.z *= inv; x0.w *= inv;
    x1.x *= inv; x1.y *= inv; x1.z *= inv; x1.w *= inv;
    ((float4*)p)[tid] = x0;
    ((float4*)p)[tid + 256] = x1;
}

// ---------------------------------------------------------------------------
// pv: per (b,h) GEMM  Ctx[m][d] = sum_k P[m][k] * V[k][d].
// P row-major [B,H,S,S]; V in [B,H,S,64]. Ctx written [B*S, D] (col=h*64+d).
// grid (1, S/64, B*H), 256 threads, 4x4 micro-tile, full N=64 per block.
// ---------------------------------------------------------------------------
__global__ __launch_bounds__(256) void pv_kernel(
    const float* __restrict__ P, const float* __restrict__ V,
    float* __restrict__ Ctx)
{
    const int bh     = blockIdx.z;
    const int tile_m = blockIdx.y * 64;
    const int b = bh >> 4;
    const int h = bh & 15;
    const int tid = threadIdx.x;
    const int tx = tid & 15;
    const int ty = tid >> 4;

    __shared__ float As[64][16];   // P tile [m][k]
    __shared__ float Bs[16][64];   // V tile [k][d]

    const float* Ph = P + (size_t)bh * S * S;
    const float* Vh = V + (((size_t)bh * S) << 6);

    float acc[4][4];
#pragma unroll
    for (int i = 0; i < 4; i++)
#pragma unroll
        for (int j = 0; j < 4; j++) acc[i][j] = 0.0f;

    for (int k0 = 0; k0 < S; k0 += 16) {
#pragma unroll
        for (int i = 0; i < 4; i++) {
            int idx = tid + i * 256;
            int r = idx >> 4, c = idx & 15;
            As[r][c] = Ph[(size_t)(tile_m + r) * S + k0 + c];
        }
        // V tile: 16x64 = 1024 floats
#pragma unroll
        for (int i = 0; i < 4; i++) {
            int idx = tid + i * 256;
            int r = idx >> 6, c = idx & 63;
            Bs[r][c] = Vh[((size_t)(k0 + r) << 6) + c];
        }
        __syncthreads();
#pragma unroll
        for (int kk = 0; kk < 16; kk++) {
            float a[4], bb[4];
#pragma unroll
            for (int i = 0; i < 4; i++) a[i] = As[ty * 4 + i][kk];
#pragma unroll
            for (int j = 0; j < 4; j++) bb[j] = Bs[kk][tx * 4 + j];
#pragma unroll
            for (int i = 0; i < 4; i++)
#pragma unroll
                for (int j = 0; j < 4; j++) acc[i][j] += a[i] * bb[j];
        }
        __syncthreads();
    }

#pragma unroll
    for (int i = 0; i < 4; i++) {
        int m = tile_m + ty * 4 + i;   // s within head
#pragma unroll
        for (int j = 0; j < 4; j++) {
            int d = tx * 4 + j;
            Ctx[((size_t)(b * S + m)) * D + h * 64 + d] = acc[i][j];
        }
    }
}

// ---------------------------------------------------------------------------
extern "C" void kernel_launch(void* const* d_in, const int* in_sizes, int n_in,
                              void* d_out, int out_size, void* d_ws, size_t ws_size,
                              hipStream_t stream)
{
    const float* q     = (const float*)d_in[0];
    const float* v     = (const float*)d_in[1];
    const float* mask  = (const float*)d_in[2];
    const float* wq_w  = (const float*)d_in[3];
    const float* wq_b  = (const float*)d_in[4];
    const float* wk_w  = (const float*)d_in[5];
    const float* wk_b  = (const float*)d_in[6];
    const float* wv_w  = (const float*)d_in[7];
    const float* wv_b  = (const float*)d_in[8];
    const float* wo_w  = (const float*)d_in[9];
    const float* wo_b  = (const float*)d_in[10];

    float* out_heads = (float*)d_out;                       // [B,S,D]
    float* out_align = (float*)d_out + (size_t)B * S * D;   // [B,H,S,S]

    const size_t qkv_elems = (size_t)B * H * S * KS;        // 4,194,304
    float* Qw  = (float*)d_ws;
    float* Kw  = Qw + qkv_elems;
    float* Vw  = Kw + qkv_elems;
    float* Ctx = Vw + qkv_elems;                            // [B*S, D]

    dim3 gemm_grid(D / 64, M_ROWS / 64);   // (16, 64)
    gemm_proj<<<gemm_grid, 256, 0, stream>>>(q, wq_w, wq_b, Qw, 1);
    gemm_proj<<<gemm_grid, 256, 0, stream>>>(v, wk_w, wk_b, Kw, 1);
    gemm_proj<<<gemm_grid, 256, 0, stream>>>(v, wv_w, wv_b, Vw, 1);

    dim3 sc_grid(S / 64, S / 64, B * H);   // (32, 32, 32)
    scores_kernel<<<sc_grid, 256, 0, stream>>>(Qw, Kw, mask, out_align);

    softmax_kernel<<<(size_t)B * H * S, 256, 0, stream>>>(out_align);

    dim3 pv_grid(1, S / 64, B * H);        // (1, 32, 32)
    pv_kernel<<<pv_grid, 256, 0, stream>>>(out_align, Vw, Ctx);

    gemm_proj<<<gemm_grid, 256, 0, stream>>>(Ctx, wo_w, wo_b, out_heads, 0);
}